// Round 6
// baseline (267.543 us; speedup 1.0000x reference)
//
#include <hip/hip_runtime.h>
#include <hip/hip_bf16.h>

#define NN 4096
#define KIN 256
#define HF 512
#define NHD 4
#define OF 128

typedef __bf16 bf16x8 __attribute__((ext_vector_type(8)));
typedef __bf16 bf16x4 __attribute__((ext_vector_type(4)));
typedef float f32x4 __attribute__((ext_vector_type(4)));

// ---------------- K0: WT[c][k] = (bf16)W[k][c], LDS-tiled ----------------
__global__ __launch_bounds__(256) void k_transpose_w(const float* __restrict__ W,
                                                     __bf16* __restrict__ WT) {
    __shared__ __bf16 tl[64][65];
    int k0 = blockIdx.x * 64, c0 = blockIdx.y * 64;
    #pragma unroll
    for (int it = 0; it < 16; ++it) {
        int idx = it * 256 + threadIdx.x;
        int kk = idx >> 6, cc = idx & 63;
        tl[kk][cc] = (__bf16)W[(size_t)(k0 + kk) * HF + c0 + cc];  // coalesced read
    }
    __syncthreads();
    #pragma unroll
    for (int it = 0; it < 16; ++it) {
        int idx = it * 256 + threadIdx.x;
        int cc = idx >> 6, kk = idx & 63;
        WT[(size_t)(c0 + cc) * KIN + k0 + kk] = tl[kk][cc];        // coalesced write
    }
}

// ---------------- K1: hbT[c][m] = sum_k x[m][k]*W[k][c], 16x16x32 MFMA ------
// A[m=lane&15][k=quad*8+j]; B[k][n=lane&15]; C/D col=lane&15, row=quad*4+reg
__global__ __launch_bounds__(256) void k_gemm_h(const float* __restrict__ x,
                                                const __bf16* __restrict__ WT,
                                                __bf16* __restrict__ hbT) {
    int lane = threadIdx.x & 63, wave = threadIdx.x >> 6;
    int m = lane & 15, quad = lane >> 4;
    int m0 = blockIdx.x * 16;                 // 256 m-tiles
    int c0 = blockIdx.y * 256 + wave * 64;    // wave covers 64 c
    f32x4 acc[4];
    #pragma unroll
    for (int nt = 0; nt < 4; ++nt) acc[nt] = (f32x4){0.f, 0.f, 0.f, 0.f};
    const float* xp = x + (size_t)(m0 + m) * KIN + quad * 8;
    #pragma unroll
    for (int kk = 0; kk < 8; ++kk) {          // K = 256 = 8 * 32
        float4 xa = *(const float4*)(xp + kk * 32);
        float4 xb = *(const float4*)(xp + kk * 32 + 4);
        bf16x8 af;
        af[0] = (__bf16)xa.x; af[1] = (__bf16)xa.y; af[2] = (__bf16)xa.z; af[3] = (__bf16)xa.w;
        af[4] = (__bf16)xb.x; af[5] = (__bf16)xb.y; af[6] = (__bf16)xb.z; af[7] = (__bf16)xb.w;
        #pragma unroll
        for (int nt = 0; nt < 4; ++nt) {
            bf16x8 bf = *(const bf16x8*)(WT + (size_t)(c0 + nt * 16 + m) * KIN + kk * 32 + quad * 8);
            acc[nt] = __builtin_amdgcn_mfma_f32_16x16x32_bf16(af, bf, acc[nt], 0, 0, 0);
        }
    }
    #pragma unroll
    for (int nt = 0; nt < 4; ++nt) {
        bf16x4 o;
        #pragma unroll
        for (int e = 0; e < 4; ++e) o[e] = (__bf16)acc[nt][e];
        *(bf16x4*)(hbT + (size_t)(c0 + nt * 16 + m) * NN + m0 + quad * 4) = o;
    }
}

// ---------------- K2: ci[h][n], cj[h][n] — 256 blocks, f-split lanes --------
__global__ __launch_bounds__(256) void k_cicj(const __bf16* __restrict__ hbT,
                                              const float* __restrict__ ai,
                                              const float* __restrict__ aj,
                                              float* __restrict__ ci,
                                              float* __restrict__ cj) {
    int h = threadIdx.x >> 6, lane = threadIdx.x & 63;
    int nl = lane & 15, fg = lane >> 4;       // 16 n x 4 f-groups
    int n = blockIdx.x * 16 + nl;
    float si = 0.f, sj = 0.f;
    for (int f0 = 0; f0 < 32; ++f0) {
        int c = h * OF + fg * 32 + f0;
        float v = (float)hbT[(size_t)c * NN + n];
        si += v * ai[c];
        sj += v * aj[c];
    }
    si += __shfl_xor(si, 16); si += __shfl_xor(si, 32);
    sj += __shfl_xor(sj, 16); sj += __shfl_xor(sj, 32);
    if (lane < 16) {
        ci[h * NN + n] = si;
        cj[h * NN + n] = sj;
    }
}

// ---------------- K3: fused attention, barrier-free j-loop ------------------
// grid (256 i-tiles of 16 rows, 4 heads); block 256 = 4 waves sharing the
// i-tile, wave w handles j-tiles jt % 4 == w. One barrier + LDS combine.
__global__ __launch_bounds__(256) void k_attn(const float* __restrict__ adj,
                                              const __bf16* __restrict__ hbT,
                                              const float* __restrict__ ci,
                                              const float* __restrict__ cj,
                                              const float* __restrict__ bias,
                                              float* __restrict__ out) {
    __shared__ float accs[4][16][129];   // [wave][i_local][f], stride 129: conflict-free
    __shared__ float denp[4][16];
    int tid = threadIdx.x;
    int lane = tid & 63, w = tid >> 6;
    int m = lane & 15, quad = lane >> 4;
    int hd = blockIdx.y;
    int ibase = blockIdx.x * 16;
    int irow = ibase + m;
    float cival = ci[hd * NN + irow];
    const float* adjp = adj + (size_t)irow * NN + quad * 8;
    const float* cjp  = cj + hd * NN + quad * 8;
    const __bf16* vbase = hbT + (size_t)(hd * OF + m) * NN + quad * 8;

    f32x4 acc[8];
    #pragma unroll
    for (int nt = 0; nt < 8; ++nt) acc[nt] = (f32x4){0.f, 0.f, 0.f, 0.f};
    float denl = 0.f;

    for (int t = 0; t < 32; ++t) {
        int j0 = (w + 4 * t) * 32;           // this wave's j-tile
        float4 a0 = *(const float4*)(adjp + j0);
        float4 a1 = *(const float4*)(adjp + j0 + 4);
        float4 c0 = *(const float4*)(cjp + j0);
        float4 c1 = *(const float4*)(cjp + j0 + 4);
        float aa[8], cc[8];
        aa[0] = a0.x; aa[1] = a0.y; aa[2] = a0.z; aa[3] = a0.w;
        aa[4] = a1.x; aa[5] = a1.y; aa[6] = a1.z; aa[7] = a1.w;
        cc[0] = c0.x; cc[1] = c0.y; cc[2] = c0.z; cc[3] = c0.w;
        cc[4] = c1.x; cc[5] = c1.y; cc[6] = c1.z; cc[7] = c1.w;
        bf16x8 af;
        #pragma unroll
        for (int u = 0; u < 8; ++u) {
            float a = aa[u];
            float s = cival + cc[u];
            s = fmaxf(s, s * 0.2f);          // leaky_relu
            s *= a;
            float p = __expf(s);             // s in ~[-4,4]: shift-free softmax safe
            denl += p;
            af[u] = (__bf16)(p * a);
        }
        const __bf16* vp = vbase + j0;
        #pragma unroll
        for (int nt = 0; nt < 8; ++nt) {
            bf16x8 bf = *(const bf16x8*)(vp + (size_t)(nt * 16) * NN);  // B[k][n=m]
            acc[nt] = __builtin_amdgcn_mfma_f32_16x16x32_bf16(af, bf, acc[nt], 0, 0, 0);
        }
    }
    // wave-partial den for row m (sum over quads)
    denl += __shfl_xor(denl, 16);
    denl += __shfl_xor(denl, 32);
    if (lane < 16) denp[w][lane] = denl;
    // dump wave-partial acc tile: C/D row = quad*4+reg (i_local), col = nt*16+m (f)
    #pragma unroll
    for (int nt = 0; nt < 8; ++nt)
        #pragma unroll
        for (int reg = 0; reg < 4; ++reg)
            accs[w][quad * 4 + reg][nt * 16 + m] = acc[nt][reg];
    __syncthreads();
    // combine 4 waves; thread -> (i_local, 8 f)
    int il = tid >> 4, f0 = (tid & 15) * 8;
    float s[8] = {0.f, 0.f, 0.f, 0.f, 0.f, 0.f, 0.f, 0.f};
    #pragma unroll
    for (int w2 = 0; w2 < 4; ++w2)
        #pragma unroll
        for (int e = 0; e < 8; ++e) s[e] += accs[w2][il][f0 + e];
    float den = denp[0][il] + denp[1][il] + denp[2][il] + denp[3][il];
    float dinv = 1.0f / den;
    float4 b0 = *(const float4*)(bias + hd * OF + f0);
    float4 b1 = *(const float4*)(bias + hd * OF + f0 + 4);
    float4 o0, o1;
    o0.x = s[0] * dinv + b0.x; o0.y = s[1] * dinv + b0.y;
    o0.z = s[2] * dinv + b0.z; o0.w = s[3] * dinv + b0.w;
    o1.x = s[4] * dinv + b1.x; o1.y = s[5] * dinv + b1.y;
    o1.z = s[6] * dinv + b1.z; o1.w = s[7] * dinv + b1.w;
    float* op = out + (size_t)(ibase + il) * HF + hd * OF + f0;
    *(float4*)op = o0;
    *(float4*)(op + 4) = o1;
}

extern "C" void kernel_launch(void* const* d_in, const int* in_sizes, int n_in,
                              void* d_out, int out_size, void* d_ws, size_t ws_size,
                              hipStream_t stream) {
    const float* x    = (const float*)d_in[0];
    const float* adj  = (const float*)d_in[1];
    const float* W    = (const float*)d_in[2];
    const float* ai   = (const float*)d_in[3];
    const float* aj   = (const float*)d_in[4];
    const float* bias = (const float*)d_in[5];
    float* out = (float*)d_out;

    char* ws = (char*)d_ws;
    // ws: WT 256KB | hbT 4MB | ci 64KB | cj 64KB   (total ~4.4MB)
    __bf16* WT  = (__bf16*)(ws);
    __bf16* hbT = (__bf16*)(ws + (1 << 18));
    float*  ci  = (float*)(ws + (1 << 18) + (1 << 22));
    float*  cj  = (float*)(ws + (1 << 18) + (1 << 22) + (1 << 16));

    k_transpose_w<<<dim3(4, 8), 256, 0, stream>>>(W, WT);
    k_gemm_h<<<dim3(256, 2), 256, 0, stream>>>(x, WT, hbT);
    k_cicj<<<256, 256, 0, stream>>>(hbT, ai, aj, ci, cj);
    k_attn<<<dim3(256, NHD), 256, 0, stream>>>(adj, hbT, ci, cj, bias, out);
}